// Round 1
// baseline (450.267 us; speedup 1.0000x reference)
//
#include <hip/hip_runtime.h>

// SSIM loss, fused separable Gaussian conv, fp32.
// Shapes fixed by reference: (32,3,512,512) fp32 inputs, scalar fp32 output.

constexpr int H   = 512;
constexpr int W   = 512;
constexpr int NCH = 96;        // 32*3 planes
constexpr int KS  = 11;
constexpr int RAD = 5;
constexpr int HO  = 502;       // H - 10 (valid conv)
constexpr int WO  = 502;
constexpr int TH  = 32;        // output tile rows per block
constexpr int TW  = 116;       // output tile cols per block (mult of 4 for aligned float4)
constexpr int RH  = 42;        // TH + 10 input region rows
constexpr int RW  = 128;       // input region cols (TW+10=126 <= 128)
constexpr int NTX = 5;         // ceil(502/116)
constexpr int NTY = 16;        // ceil(502/32)

__device__ __forceinline__ unsigned fkey(float f) {
  unsigned u = __float_as_uint(f);
  return (u & 0x80000000u) ? ~u : (u | 0x80000000u);
}
__device__ __forceinline__ float funkey(unsigned k) {
  unsigned u = (k & 0x80000000u) ? (k & 0x7FFFFFFFu) : ~k;
  return __uint_as_float(u);
}

__global__ void init_ws_kernel(unsigned* ws) {
  ws[0] = 0u;             // running max key
  ws[1] = 0xFFFFFFFFu;    // running min key
  ((float*)ws)[2] = 0.0f; // ssim sum
}

__global__ __launch_bounds__(256) void minmax_kernel(
    const float4* __restrict__ x, unsigned* __restrict__ ws, int n4) {
  int tid = threadIdx.x;
  int gid = blockIdx.x * blockDim.x + tid;
  int stride = gridDim.x * blockDim.x;
  float mx = -3.4e38f, mn = 3.4e38f;
  for (int i = gid; i < n4; i += stride) {
    float4 v = x[i];
    mx = fmaxf(mx, fmaxf(fmaxf(v.x, v.y), fmaxf(v.z, v.w)));
    mn = fminf(mn, fminf(fminf(v.x, v.y), fminf(v.z, v.w)));
  }
  #pragma unroll
  for (int off = 32; off; off >>= 1) {
    mx = fmaxf(mx, __shfl_down(mx, off));
    mn = fminf(mn, __shfl_down(mn, off));
  }
  __shared__ float smx[4], smn[4];
  int lane = tid & 63, wid = tid >> 6;
  if (lane == 0) { smx[wid] = mx; smn[wid] = mn; }
  __syncthreads();
  if (tid == 0) {
    mx = fmaxf(fmaxf(smx[0], smx[1]), fmaxf(smx[2], smx[3]));
    mn = fminf(fminf(smn[0], smn[1]), fminf(smn[2], smn[3]));
    atomicMax(&ws[0], fkey(mx));
    atomicMin(&ws[1], fkey(mn));
  }
}

__global__ __launch_bounds__(256) void ssim_kernel(
    const float* __restrict__ img1, const float* __restrict__ img2,
    const unsigned* __restrict__ wsk, float* __restrict__ sum_out) {
  __shared__ __align__(16) float s1[RH][RW];
  __shared__ __align__(16) float s2[RH][RW];
  __shared__ __align__(16) float vr[8][5][RW];  // 8 rows of vertical conv results
  __shared__ float bsum[4];

  const int tid = threadIdx.x;
  const int tx = blockIdx.x, ty = blockIdx.y, pl = blockIdx.z;
  const int row0 = ty * TH, col0 = tx * TW;
  const float* p1 = img1 + (size_t)pl * H * W;
  const float* p2 = img2 + (size_t)pl * H * W;

  // 1-D gaussian weights (fp32, matches reference within ~1e-7)
  float gw[KS];
  {
    float s = 0.f;
    #pragma unroll
    for (int k = 0; k < KS; ++k) {
      float d = (float)(k - RAD);
      gw[k] = expf(-(d * d) * (1.0f / 4.5f));
      s += gw[k];
    }
    float inv = 1.0f / s;
    #pragma unroll
    for (int k = 0; k < KS; ++k) gw[k] *= inv;
  }

  // dynamic range -> C1, C2
  const float maxv = funkey(wsk[0]);
  const float minv = funkey(wsk[1]);
  const float L = (maxv > 128.0f ? 255.0f : 1.0f) - (minv < -0.5f ? -1.0f : 0.0f);
  float C1 = 0.01f * L; C1 = C1 * C1;
  float C2 = 0.03f * L; C2 = C2 * C2;

  // stage input region (zero-fill out of range; only feeds masked outputs)
  for (int idx = tid; idx < RH * 32; idx += 256) {
    int r = idx >> 5, c4 = idx & 31;
    int gr = row0 + r, gc = col0 + (c4 << 2);
    float4 a = make_float4(0.f, 0.f, 0.f, 0.f);
    float4 b = a;
    if (gr < H && gc < W) {
      a = *reinterpret_cast<const float4*>(p1 + gr * W + gc);
      b = *reinterpret_cast<const float4*>(p2 + gr * W + gc);
    }
    *reinterpret_cast<float4*>(&s1[r][c4 << 2]) = a;
    *reinterpret_cast<float4*>(&s2[r][c4 << 2]) = b;
  }
  __syncthreads();

  float lsum = 0.f;

  for (int p = 0; p < 4; ++p) {
    // ---- vertical conv: 8 output rows/pass, 4-row bands per half-block ----
    {
      const int half = tid >> 7;       // 0..1
      const int c = tid & 127;
      const int r0 = p * 8 + half * 4; // local output row of band start
      float acc[4][5];
      #pragma unroll
      for (int dr = 0; dr < 4; ++dr)
        #pragma unroll
        for (int q = 0; q < 5; ++q) acc[dr][q] = 0.f;

      #pragma unroll
      for (int ir = 0; ir < 14; ++ir) {
        float a = s1[r0 + ir][c];
        float b = s2[r0 + ir][c];
        float aa = a * a, bb = b * b, ab = a * b;
        #pragma unroll
        for (int dr = 0; dr < 4; ++dr) {
          int k = ir - dr;
          if (k >= 0 && k < KS) {
            float w = gw[k];
            acc[dr][0] = fmaf(w, a,  acc[dr][0]);
            acc[dr][1] = fmaf(w, b,  acc[dr][1]);
            acc[dr][2] = fmaf(w, aa, acc[dr][2]);
            acc[dr][3] = fmaf(w, bb, acc[dr][3]);
            acc[dr][4] = fmaf(w, ab, acc[dr][4]);
          }
        }
      }
      #pragma unroll
      for (int dr = 0; dr < 4; ++dr)
        #pragma unroll
        for (int q = 0; q < 5; ++q)
          vr[half * 4 + dr][q][c] = acc[dr][q];
    }
    __syncthreads();

    // ---- horizontal conv + SSIM combine: 8 rows x 29 segments of 4 cols ----
    {
      const int rh = tid >> 5;  // 0..7
      const int s  = tid & 31;  // segment
      if (s < 29) {             // 29*4 == TW; also keeps reads in bounds
        float hv[5][4];
        #pragma unroll
        for (int q = 0; q < 5; ++q) {
          const float* vp = &vr[rh][q][s << 2];
          float4 A  = *reinterpret_cast<const float4*>(vp);
          float4 Bv = *reinterpret_cast<const float4*>(vp + 4);
          float4 Cv = *reinterpret_cast<const float4*>(vp + 8);
          float2 Dv = *reinterpret_cast<const float2*>(vp + 12);
          float v[14] = {A.x, A.y, A.z, A.w, Bv.x, Bv.y, Bv.z, Bv.w,
                         Cv.x, Cv.y, Cv.z, Cv.w, Dv.x, Dv.y};
          #pragma unroll
          for (int j = 0; j < 4; ++j) {
            float h = 0.f;
            #pragma unroll
            for (int k = 0; k < KS; ++k) h = fmaf(gw[k], v[j + k], h);
            hv[q][j] = h;
          }
        }
        const int orow = row0 + p * 8 + rh;
        #pragma unroll
        for (int j = 0; j < 4; ++j) {
          int ocol = col0 + (s << 2) + j;
          if (orow < HO && ocol < WO) {
            float mu1 = hv[0][j], mu2 = hv[1][j];
            float m11 = mu1 * mu1, m22 = mu2 * mu2, m12 = mu1 * mu2;
            float s11 = hv[2][j] - m11;
            float s22 = hv[3][j] - m22;
            float s12 = hv[4][j] - m12;
            float num = (2.f * m12 + C1) * (2.f * s12 + C2);
            float den = (m11 + m22 + C1) * (s11 + s22 + C2);
            lsum += num * __builtin_amdgcn_rcpf(den);
          }
        }
      }
    }
    __syncthreads();
  }

  // block reduction -> one atomic per block
  #pragma unroll
  for (int off = 32; off; off >>= 1) lsum += __shfl_down(lsum, off);
  int lane = tid & 63, wid = tid >> 6;
  if (lane == 0) bsum[wid] = lsum;
  __syncthreads();
  if (tid == 0) atomicAdd(sum_out, bsum[0] + bsum[1] + bsum[2] + bsum[3]);
}

__global__ void finalize_kernel(const float* __restrict__ sum, float* __restrict__ out) {
  out[0] = 1.0f - sum[0] * (1.0f / 24192384.0f);  // 96*502*502
}

extern "C" void kernel_launch(void* const* d_in, const int* in_sizes, int n_in,
                              void* d_out, int out_size, void* d_ws, size_t ws_size,
                              hipStream_t stream) {
  const float* img1 = (const float*)d_in[0];
  const float* img2 = (const float*)d_in[1];
  float* out = (float*)d_out;
  unsigned* ws = (unsigned*)d_ws;

  init_ws_kernel<<<1, 1, 0, stream>>>(ws);

  int n4 = in_sizes[0] >> 2;
  minmax_kernel<<<1024, 256, 0, stream>>>((const float4*)img1, ws, n4);

  dim3 grid(NTX, NTY, NCH);
  ssim_kernel<<<grid, 256, 0, stream>>>(img1, img2, ws, (float*)ws + 2);

  finalize_kernel<<<1, 1, 0, stream>>>((const float*)ws + 2, out);
}

// Round 2
// 400.085 us; speedup vs baseline: 1.1254x; 1.1254x over previous
//
#include <hip/hip_runtime.h>

// SSIM loss, register-streamed vertical conv + LDS horizontal conv, fp32.
// Shapes fixed by reference: (32,3,512,512) fp32 inputs, scalar fp32 output.

constexpr int H   = 512;
constexpr int W   = 512;
constexpr int NCH = 96;        // 32*3 planes
constexpr int KS  = 11;
constexpr int HO  = 502;       // H - 10 (valid conv)
constexpr int WO  = 502;
constexpr int PCOLS = 128;     // input cols per block == threads
constexpr int OCOLS = 118;     // output cols per block
constexpr int OROWS = 128;     // output rows per block (y-band)
constexpr int NG    = 13;      // row groups of 11 (covers o_local 0..127)
constexpr int NBX   = 5;       // ceil(502/118)
constexpr int NBY   = 4;       // ceil(502/128)
constexpr int HPAD  = 132;     // hbuf row padding (floats)

__device__ __forceinline__ unsigned fkey(float f) {
  unsigned u = __float_as_uint(f);
  return (u & 0x80000000u) ? ~u : (u | 0x80000000u);
}
__device__ __forceinline__ float funkey(unsigned k) {
  unsigned u = (k & 0x80000000u) ? (k & 0x7FFFFFFFu) : ~k;
  return __uint_as_float(u);
}

__global__ void init_ws_kernel(unsigned* ws) {
  ws[0] = 0u;             // running max key
  ws[1] = 0xFFFFFFFFu;    // running min key
  ((float*)ws)[2] = 0.0f; // ssim sum
}

__global__ __launch_bounds__(256) void minmax_kernel(
    const float4* __restrict__ x, unsigned* __restrict__ ws, int n4) {
  int tid = threadIdx.x;
  int gid = blockIdx.x * blockDim.x + tid;
  int stride = gridDim.x * blockDim.x;
  float mx = -3.4e38f, mn = 3.4e38f;
  for (int i = gid; i < n4; i += stride) {
    float4 v = x[i];
    mx = fmaxf(mx, fmaxf(fmaxf(v.x, v.y), fmaxf(v.z, v.w)));
    mn = fminf(mn, fminf(fminf(v.x, v.y), fminf(v.z, v.w)));
  }
  #pragma unroll
  for (int off = 32; off; off >>= 1) {
    mx = fmaxf(mx, __shfl_down(mx, off));
    mn = fminf(mn, __shfl_down(mn, off));
  }
  __shared__ float smx[4], smn[4];
  int lane = tid & 63, wid = tid >> 6;
  if (lane == 0) { smx[wid] = mx; smn[wid] = mn; }
  __syncthreads();
  if (tid == 0) {
    mx = fmaxf(fmaxf(smx[0], smx[1]), fmaxf(smx[2], smx[3]));
    mn = fminf(fminf(smn[0], smn[1]), fminf(smn[2], smn[3]));
    atomicMax(&ws[0], fkey(mx));
    atomicMin(&ws[1], fkey(mn));
  }
}

__global__ __launch_bounds__(128) void ssim_kernel(
    const float* __restrict__ img1, const float* __restrict__ img2,
    const unsigned* __restrict__ wsk, float* __restrict__ sum_out) {
  // hbuf: 11 completed vertical-conv rows x 5 quantities x padded width
  __shared__ __align__(16) float hbuf[11][5][HPAD];
  __shared__ float bsum[2];

  const int tid = threadIdx.x;
  const int bx = blockIdx.x, by = blockIdx.y, pl = blockIdx.z;
  const int col0 = bx * OCOLS;
  const int row0 = by * OROWS;
  const int col  = col0 + tid;           // this thread's input column
  const bool colok = (col < W);
  const float* p1 = img1 + (size_t)pl * H * W;
  const float* p2 = img2 + (size_t)pl * H * W;

  // 1-D gaussian weights (identical formula to validated R1 kernel)
  float gw[KS];
  {
    float s = 0.f;
    #pragma unroll
    for (int k = 0; k < KS; ++k) {
      float d = (float)(k - 5);
      gw[k] = expf(-(d * d) * (1.0f / 4.5f));
      s += gw[k];
    }
    float inv = 1.0f / s;
    #pragma unroll
    for (int k = 0; k < KS; ++k) gw[k] *= inv;
  }

  // dynamic range -> C1, C2
  const float maxv = funkey(wsk[0]);
  const float minv = funkey(wsk[1]);
  const float L = (maxv > 128.0f ? 255.0f : 1.0f) - (minv < -0.5f ? -1.0f : 0.0f);
  float C1 = 0.01f * L; C1 = C1 * C1;
  float C2 = 0.03f * L; C2 = C2 * C2;

  // 11-slot rotating vertical band accumulators x 5 quantities (all static idx)
  float acc[11][5];
  #pragma unroll
  for (int s = 0; s < 11; ++s)
    #pragma unroll
    for (int q = 0; q < 5; ++q) acc[s][q] = 0.f;

  float lsum = 0.f;

  #pragma unroll 1
  for (int g = 0; g < NG; ++g) {
    const int rbase = row0 + 11 * g;

    // ---- load this group's 11 input rows to registers (batched, indep) ----
    float ra[11], rb[11];
    #pragma unroll
    for (int p = 0; p < 11; ++p) {
      const int r = rbase + p;
      const bool ok = colok && (r < H);
      const float* a1 = p1 + (size_t)r * W + col;
      const float* a2 = p2 + (size_t)r * W + col;
      ra[p] = ok ? *a1 : 0.f;
      rb[p] = ok ? *a2 : 0.f;
    }

    // ---- vertical conv: each row feeds all 11 slots; one slot completes ----
    #pragma unroll
    for (int p = 0; p < 11; ++p) {
      const float a = ra[p], b = rb[p];
      const float aa = a * a, bb = b * b, ab = a * b;
      #pragma unroll
      for (int s = 0; s < 11; ++s) {
        const float w = gw[(p - s + 11) % 11];
        acc[s][0] = fmaf(w, a,  acc[s][0]);
        acc[s][1] = fmaf(w, b,  acc[s][1]);
        acc[s][2] = fmaf(w, aa, acc[s][2]);
        acc[s][3] = fmaf(w, bb, acc[s][3]);
        acc[s][4] = fmaf(w, ab, acc[s][4]);
      }
      // slot (p+1)%11 just received its gw[10] tap -> complete; emit & reset.
      // emitted output row: o_local = 11g + p - 10  (masked in horizontal)
      constexpr int ES[11] = {1,2,3,4,5,6,7,8,9,10,0};
      const int es = ES[p];
      #pragma unroll
      for (int q = 0; q < 5; ++q) {
        hbuf[p][q][tid] = acc[es][q];
        acc[es][q] = 0.f;
      }
    }
    __syncthreads();

    // ---- horizontal conv + SSIM: 11 rows x 30 segments of 4 cols ----
    #pragma unroll
    for (int it = 0; it < 3; ++it) {
      const int t  = it * 128 + tid;
      const int rr = t >> 5;       // 0..11
      const int sg = t & 31;       // 0..31
      const int ol = 11 * g - 10 + rr;
      const int orow = row0 + ol;
      if (rr < 11 && sg < 30 && ol >= 0 && ol < OROWS && orow < HO) {
        float hv[5][4];
        #pragma unroll
        for (int q = 0; q < 5; ++q) {
          const float* vp = &hbuf[rr][q][sg << 2];
          float4 A  = *reinterpret_cast<const float4*>(vp);
          float4 Bv = *reinterpret_cast<const float4*>(vp + 4);
          float4 Cv = *reinterpret_cast<const float4*>(vp + 8);
          float2 Dv = *reinterpret_cast<const float2*>(vp + 12);
          float v[14] = {A.x, A.y, A.z, A.w, Bv.x, Bv.y, Bv.z, Bv.w,
                         Cv.x, Cv.y, Cv.z, Cv.w, Dv.x, Dv.y};
          #pragma unroll
          for (int j = 0; j < 4; ++j) {
            float h = 0.f;
            #pragma unroll
            for (int k = 0; k < KS; ++k) h = fmaf(gw[k], v[j + k], h);
            hv[q][j] = h;
          }
        }
        #pragma unroll
        for (int j = 0; j < 4; ++j) {
          const int oc = (sg << 2) + j;
          const int ocol = col0 + oc;
          if (oc < OCOLS && ocol < WO) {
            float mu1 = hv[0][j], mu2 = hv[1][j];
            float m11 = mu1 * mu1, m22 = mu2 * mu2, m12 = mu1 * mu2;
            float s11 = hv[2][j] - m11;
            float s22 = hv[3][j] - m22;
            float s12 = hv[4][j] - m12;
            float num = (2.f * m12 + C1) * (2.f * s12 + C2);
            float den = (m11 + m22 + C1) * (s11 + s22 + C2);
            lsum += num * __builtin_amdgcn_rcpf(den);
          }
        }
      }
    }
    __syncthreads();  // protect hbuf before next group's emissions
  }

  // block reduction -> one atomic per block
  #pragma unroll
  for (int off = 32; off; off >>= 1) lsum += __shfl_down(lsum, off);
  const int lane = tid & 63, wid = tid >> 6;
  if (lane == 0) bsum[wid] = lsum;
  __syncthreads();
  if (tid == 0) atomicAdd(sum_out, bsum[0] + bsum[1]);
}

__global__ void finalize_kernel(const float* __restrict__ sum, float* __restrict__ out) {
  out[0] = 1.0f - sum[0] * (1.0f / 24192384.0f);  // 96*502*502
}

extern "C" void kernel_launch(void* const* d_in, const int* in_sizes, int n_in,
                              void* d_out, int out_size, void* d_ws, size_t ws_size,
                              hipStream_t stream) {
  const float* img1 = (const float*)d_in[0];
  const float* img2 = (const float*)d_in[1];
  float* out = (float*)d_out;
  unsigned* ws = (unsigned*)d_ws;

  init_ws_kernel<<<1, 1, 0, stream>>>(ws);

  int n4 = in_sizes[0] >> 2;
  minmax_kernel<<<1024, 256, 0, stream>>>((const float4*)img1, ws, n4);

  dim3 grid(NBX, NBY, NCH);
  ssim_kernel<<<grid, 128, 0, stream>>>(img1, img2, ws, (float*)ws + 2);

  finalize_kernel<<<1, 1, 0, stream>>>((const float*)ws + 2, out);
}